// Round 4
// baseline (5225.881 us; speedup 1.0000x reference)
//
#include <hip/hip_runtime.h>
#include <hip/hip_bf16.h>
#include <math.h>

#define T 128
#define KN 14      // graph nodes
#define HM 64
#define HF 32
#define F 1024
#define TK (T*KN)   // 1792
#define KF (KN*F)   // 14336

typedef __attribute__((ext_vector_type(8))) short bf16x8;
typedef __attribute__((ext_vector_type(4))) float f32x4;

static __device__ __forceinline__ short f2bs(float f) {
  __hip_bfloat16 h = __float2bfloat16(f);
  return *reinterpret_cast<short*>(&h);
}

// ---------------- prep: An (gcn_norm) + reset flags + barrier init ----------------
__global__ void prep_kernel(const float* __restrict__ A, const int* __restrict__ vid,
                            float* __restrict__ An, int* __restrict__ rf, int* __restrict__ rb,
                            int* __restrict__ bar) {
  __shared__ float dinv[KN];
  int tid = threadIdx.x;
  if (tid == 0) *bar = 0;
  if (tid < KN) {
    float s = 0.f;
    for (int j = 0; j < KN; ++j) {
      float ab = (A[tid*KN + j] != 0.f) ? 1.f : 0.f;
      if (j == tid) ab += 1.f;
      s += ab;
    }
    dinv[tid] = 1.0f / sqrtf(s);
  }
  __syncthreads();
  if (tid < KN*KN) {
    int i = tid / KN, j = tid % KN;
    float ab = (A[i*KN + j] != 0.f) ? 1.f : 0.f;
    if (i == j) ab += 1.f;
    An[tid] = dinv[i] * ab * dinv[j];
  }
  if (tid < T) {
    rf[tid] = (tid == 0) || (vid[tid] != vid[tid-1]);
    rb[tid] = (tid == 0) || (vid[T-1-tid] != vid[T-tid]);
  }
}

// ---------------- downsample: x (T,K,64,64) -> feat_bf (T,K,1024) ----------------
__global__ void downsample_kernel(const float* __restrict__ x, __hip_bfloat16* __restrict__ feat) {
  __shared__ float xt[HM*HM];
  int b = blockIdx.x; // t*KN + k
  const float* xp = x + (size_t)b*HM*HM;
  int tid = threadIdx.x;
  #pragma unroll
  for (int i = 0; i < 4; ++i)
    ((float4*)xt)[tid + i*256] = ((const float4*)xp)[tid + i*256];
  __syncthreads();
  const float r = 63.0f/31.0f;
  __hip_bfloat16* fp = feat + (size_t)b*F;
  #pragma unroll
  for (int i = 0; i < 4; ++i) {
    int idx = tid + i*256;
    int o = idx >> 5, p = idx & 31;
    float co = (float)o * r; int io = (int)floorf(co); int io1 = min(io+1, HM-1); float wo = co - (float)io;
    float cp = (float)p * r; int jp = (int)floorf(cp); int jp1 = min(jp+1, HM-1); float wp = cp - (float)jp;
    float v = (1.f-wo)*((1.f-wp)*xt[io*HM+jp]  + wp*xt[io*HM+jp1])
            +      wo *((1.f-wp)*xt[io1*HM+jp] + wp*xt[io1*HM+jp1]);
    fp[idx] = __float2bfloat16(v);
  }
}

// ---------------- convert+transpose one FxF fp32 block -> bf16 (dst = src^T) ----------------
__global__ void convt_kernel(const float* __restrict__ src, __hip_bfloat16* __restrict__ dst) {
  __shared__ float tile[32][33];
  int bx = blockIdx.x, by = blockIdx.y;
  int tx = threadIdx.x & 31, ty = threadIdx.x >> 5; // ty 0..7
  #pragma unroll
  for (int i = 0; i < 4; ++i)
    tile[ty + i*8][tx] = src[(size_t)(by*32 + ty + i*8)*F + bx*32 + tx];
  __syncthreads();
  #pragma unroll
  for (int i = 0; i < 4; ++i)
    dst[(size_t)(bx*32 + ty + i*8)*F + by*32 + tx] = __float2bfloat16(tile[tx][ty + i*8]);
}

// ---------------- bf16 MFMA GEMM: C(M,N) = A(M,K) @ Bt(N,K)^T (+bias) ----------------
template<int OUT_BF16>
__global__ __launch_bounds__(256) void gemm_mfma(
    const __hip_bfloat16* __restrict__ A, const __hip_bfloat16* __restrict__ Bt,
    const float* __restrict__ bias, void* __restrict__ C, int ldc) {
  const int Kd = 1024;
  __shared__ short As[128][40]; // 32 used + pad
  __shared__ short Bs[128][40];
  int tid = threadIdx.x;
  int wave = tid >> 6, lane = tid & 63;
  int mBase = blockIdx.y * 128, nBase = blockIdx.x * 128;
  int srow = tid >> 2;          // 0..63
  int scol = (tid & 3) * 8;     // 0,8,16,24
  int mW = (wave >> 1) * 64, nW = (wave & 1) * 64;
  int fr = lane & 15;
  int fk = (lane >> 4) * 8;
  f32x4 acc[4][4];
  #pragma unroll
  for (int i = 0; i < 4; ++i)
    #pragma unroll
    for (int j = 0; j < 4; ++j)
      acc[i][j] = (f32x4){0.f, 0.f, 0.f, 0.f};
  for (int k0 = 0; k0 < Kd; k0 += 32) {
    float4 a0 = *(const float4*)(A  + (size_t)(mBase + srow)*Kd + k0 + scol);
    float4 a1 = *(const float4*)(A  + (size_t)(mBase + srow + 64)*Kd + k0 + scol);
    float4 b0 = *(const float4*)(Bt + (size_t)(nBase + srow)*Kd + k0 + scol);
    float4 b1 = *(const float4*)(Bt + (size_t)(nBase + srow + 64)*Kd + k0 + scol);
    __syncthreads();
    *(float4*)&As[srow][scol] = a0;
    *(float4*)&As[srow+64][scol] = a1;
    *(float4*)&Bs[srow][scol] = b0;
    *(float4*)&Bs[srow+64][scol] = b1;
    __syncthreads();
    bf16x8 af[4], bfr[4];
    #pragma unroll
    for (int i = 0; i < 4; ++i) af[i]  = *(const bf16x8*)&As[mW + i*16 + fr][fk];
    #pragma unroll
    for (int j = 0; j < 4; ++j) bfr[j] = *(const bf16x8*)&Bs[nW + j*16 + fr][fk];
    #pragma unroll
    for (int i = 0; i < 4; ++i)
      #pragma unroll
      for (int j = 0; j < 4; ++j)
        acc[i][j] = __builtin_amdgcn_mfma_f32_16x16x32_bf16(af[i], bfr[j], acc[i][j], 0, 0, 0);
  }
  int rq = (lane >> 4) * 4;
  int cl = lane & 15;
  float bv[4];
  #pragma unroll
  for (int j = 0; j < 4; ++j) bv[j] = bias ? bias[nBase + nW + j*16 + cl] : 0.f;
  #pragma unroll
  for (int i = 0; i < 4; ++i) {
    #pragma unroll
    for (int r = 0; r < 4; ++r) {
      int row = mBase + mW + i*16 + rq + r;
      #pragma unroll
      for (int j = 0; j < 4; ++j) {
        int col = nBase + nW + j*16 + cl;
        float v = acc[i][j][r] + bv[j];
        if (OUT_BF16)
          ((__hip_bfloat16*)C)[(size_t)row*ldc + col] = __float2bfloat16(v);
        else
          ((float*)C)[(size_t)row*ldc + col] = v;
      }
    }
  }
}

// ---------------- An-mix over node dim (+bias, opt relu), bf16 in/out ----------------
__global__ void anmix_kernel(const __hip_bfloat16* __restrict__ in, const float* __restrict__ An,
                             const float* __restrict__ bias, __hip_bfloat16* __restrict__ out, int relu) {
  __shared__ float an[KN*KN];
  int t = blockIdx.x, tid = threadIdx.x;
  if (tid < KN*KN) an[tid] = An[tid];
  __syncthreads();
  const __hip_bfloat16* ip = in + (size_t)t*KF;
  __hip_bfloat16* op = out + (size_t)t*KF;
  #pragma unroll
  for (int i = 0; i < 4; ++i) {
    int f = tid + i*256;
    float v[KN];
    #pragma unroll
    for (int j = 0; j < KN; ++j) v[j] = __bfloat162float(ip[j*F + f]);
    float bsv = bias ? bias[f] : 0.f;
    #pragma unroll
    for (int k = 0; k < KN; ++k) {
      float s = bsv;
      #pragma unroll
      for (int j = 0; j < KN; ++j) s = fmaf(an[k*KN+j], v[j], s);
      if (relu) s = fmaxf(s, 0.f);
      op[k*F + f] = __float2bfloat16(s);
    }
  }
}

// ---------------- persistent GRU scan: whole T loop, both dirs, 1 dispatch ----------------
#define NBLK 32
__global__ __launch_bounds__(256) void scan_persist(
    float* __restrict__ Hstf, float* __restrict__ Hstb,
    const short* __restrict__ wScan,
    const float* __restrict__ Pf0, const float* __restrict__ Pf1, const float* __restrict__ Pf2,
    const float* __restrict__ Pb0, const float* __restrict__ Pb1, const float* __restrict__ Pb2,
    const int* __restrict__ rf, const int* __restrict__ rb,
    float* __restrict__ Rbuf, int* __restrict__ bar) {
  int bx = blockIdx.x;     // 0..31
  int d = bx >> 4;
  int cb = bx & 15;        // 64-col chunk
  int tid = threadIdx.x;
  int wave = tid >> 6, lane = tid & 63;
  int cl = lane & 15;
  int kq = (lane >> 4) * 8;
  int rq = (lane >> 4) * 4;
  int colg = cb*64 + wave*16 + cl;

  float* Hst = d ? Hstb : Hstf;
  const int* rs = d ? rb : rf;
  const float* P0base = d ? Pb0 : Pf0;
  const float* P1base = d ? Pb1 : Pf1;
  const float* P2base = d ? Pb2 : Pf2;
  float* Rme = Rbuf + (size_t)d*KF;
  const short* W0 = wScan + ((size_t)(d*3 + 0))*F*F + (size_t)colg*F + kq;
  const short* W1 = wScan + ((size_t)(d*3 + 1))*F*F + (size_t)colg*F + kq;
  const short* W2 = wScan + ((size_t)(d*3 + 2))*F*F + (size_t)colg*F + kq;

  __shared__ short Ash[16][1032];
  // zero pad rows 14,15 once (never touched again)
  #pragma unroll
  for (int i = 0; i < 8; ++i) {
    int e = tid + i*256;          // 0..2047
    Ash[14 + (e >> 10)][e & 1023] = 0;
  }

  int target = 0;
  for (int t = 0; t < T; ++t) {
    int reset = rs[t];
    int tt = d ? (T-1-t) : t;
    int prev = d ? (tt+1) : (tt-1);
    const float* H = Hst + (size_t)prev*KF;

    // ---- phase A: Z (kept in regs), R (to global) ----
    f32x4 accZ = (f32x4){0.f,0.f,0.f,0.f};
    f32x4 accR = (f32x4){0.f,0.f,0.f,0.f};
    if (!reset) {
      #pragma unroll
      for (int i = 0; i < 14; ++i) {
        int e4 = tid + i*256;         // float4 index 0..3583
        float4 v = ((const float4*)H)[e4];
        int e = e4 * 4;
        short4 s; s.x = f2bs(v.x); s.y = f2bs(v.y); s.z = f2bs(v.z); s.w = f2bs(v.w);
        *(short4*)&Ash[e >> 10][e & 1023] = s;
      }
      __syncthreads();
      #pragma unroll 8
      for (int kc = 0; kc < 32; ++kc) {
        bf16x8 a  = *(const bf16x8*)&Ash[cl][kc*32 + kq];
        bf16x8 b0 = *(const bf16x8*)(W0 + kc*32);
        bf16x8 b1 = *(const bf16x8*)(W1 + kc*32);
        accZ = __builtin_amdgcn_mfma_f32_16x16x32_bf16(a, b0, accZ, 0, 0, 0);
        accR = __builtin_amdgcn_mfma_f32_16x16x32_bf16(a, b1, accR, 0, 0, 0);
      }
    }
    const float* P0 = P0base + (size_t)tt*KF;
    const float* P1 = P1base + (size_t)tt*KF;
    float z[4];
    #pragma unroll
    for (int r = 0; r < 4; ++r) {
      int node = rq + r;
      if (node < KN) {
        z[r] = 1.f / (1.f + expf(-(P0[node*F + colg] + accZ[r])));
        float rr = 1.f / (1.f + expf(-(P1[node*F + colg] + accR[r])));
        Rme[node*F + colg] = rr;
      }
    }
    target += NBLK;
    { // grid barrier
      __threadfence();
      __syncthreads();
      if (tid == 0) {
        __hip_atomic_fetch_add(bar, 1, __ATOMIC_ACQ_REL, __HIP_MEMORY_SCOPE_AGENT);
        while (__hip_atomic_load(bar, __ATOMIC_ACQUIRE, __HIP_MEMORY_SCOPE_AGENT) < target)
          __builtin_amdgcn_s_sleep(1);
      }
      __syncthreads();
      __threadfence();
    }

    // ---- phase B: Ht, Hn ----
    f32x4 acc = (f32x4){0.f,0.f,0.f,0.f};
    if (!reset) {
      #pragma unroll
      for (int i = 0; i < 14; ++i) {
        int e4 = tid + i*256;
        float4 v = ((const float4*)H)[e4];
        float4 rv = ((const float4*)Rme)[e4];
        int e = e4 * 4;
        short4 s;
        s.x = f2bs(v.x * rv.x); s.y = f2bs(v.y * rv.y);
        s.z = f2bs(v.z * rv.z); s.w = f2bs(v.w * rv.w);
        *(short4*)&Ash[e >> 10][e & 1023] = s;
      }
      __syncthreads();
      #pragma unroll 8
      for (int kc = 0; kc < 32; ++kc) {
        bf16x8 a = *(const bf16x8*)&Ash[cl][kc*32 + kq];
        bf16x8 b = *(const bf16x8*)(W2 + kc*32);
        acc = __builtin_amdgcn_mfma_f32_16x16x32_bf16(a, b, acc, 0, 0, 0);
      }
    }
    const float* P2 = P2base + (size_t)tt*KF;
    #pragma unroll
    for (int r = 0; r < 4; ++r) {
      int node = rq + r;
      if (node < KN) {
        float ht = tanhf(P2[node*F + colg] + acc[r]);
        float heff = reset ? 0.f : H[node*F + colg];
        float hn = z[r]*heff + (1.f - z[r])*ht;
        Hst[(size_t)tt*KF + node*F + colg] = hn;
      }
    }
    target += NBLK;
    if (t < T-1) { // grid barrier (skip after last step)
      __threadfence();
      __syncthreads();
      if (tid == 0) {
        __hip_atomic_fetch_add(bar, 1, __ATOMIC_ACQ_REL, __HIP_MEMORY_SCOPE_AGENT);
        while (__hip_atomic_load(bar, __ATOMIC_ACQUIRE, __HIP_MEMORY_SCOPE_AGENT) < target)
          __builtin_amdgcn_s_sleep(1);
      }
      __syncthreads();
      __threadfence();
    }
  }
}

// ---------------- upsample + sigmoid: (T,K,32,32)->(T,1,K,64,64) ----------------
__global__ void upsample_kernel(const float* __restrict__ Hf, const float* __restrict__ Hb,
                                float* __restrict__ out) {
  __shared__ float h[HF*HF];
  int b = blockIdx.x; // t*KN + k
  int tid = threadIdx.x;
  #pragma unroll
  for (int i = 0; i < 4; ++i) {
    int idx = tid + i*256;
    h[idx] = Hf[(size_t)b*F + idx] + Hb[(size_t)b*F + idx];
  }
  __syncthreads();
  const float r = 31.0f/63.0f;
  float* op = out + (size_t)b*HM*HM;
  #pragma unroll
  for (int i = 0; i < 16; ++i) {
    int idx = tid + i*256;
    int o = idx >> 6, p = idx & 63;
    float co = (float)o * r; int io = (int)floorf(co); int io1 = min(io+1, HF-1); float wo = co - (float)io;
    float cp = (float)p * r; int jp = (int)floorf(cp); int jp1 = min(jp+1, HF-1); float wp = cp - (float)jp;
    float v = (1.f-wo)*((1.f-wp)*h[io*HF+jp]  + wp*h[io*HF+jp1])
            +      wo *((1.f-wp)*h[io1*HF+jp] + wp*h[io1*HF+jp1]);
    op[idx] = 1.f / (1.f + expf(-v));
  }
}

extern "C" void kernel_launch(void* const* d_in, const int* in_sizes, int n_in,
                              void* d_out, int out_size, void* d_ws, size_t ws_size,
                              hipStream_t stream) {
  const float* x      = (const float*)d_in[0];
  const float* A      = (const float*)d_in[1];
  const float* gcn_W  = (const float*)d_in[2];
  const float* gcn_b  = (const float*)d_in[3];
  const float* tf_gW  = (const float*)d_in[4];
  const float* tf_gb  = (const float*)d_in[5];
  const float* tf_lW  = (const float*)d_in[6];
  const float* tf_lb  = (const float*)d_in[7];
  const float* tb_gW  = (const float*)d_in[8];
  const float* tb_gb  = (const float*)d_in[9];
  const float* tb_lW  = (const float*)d_in[10];
  const float* tb_lb  = (const float*)d_in[11];
  const int*   vid    = (const int*)d_in[12];
  float* out = (float*)d_out;

  float* ws = (float*)d_ws;
  float* An = ws;                  // 196 floats
  int* rf = (int*)(ws + 256);      // 128 ints
  int* rb = (int*)(ws + 512);      // 128 ints
  int* bar = (int*)(ws + 768);     // barrier counter
  const size_t SEG = (size_t)TK * F;  // 1,835,008
  float* p = ws + 1024;
  float* Pf[3]; float* Pb[3];
  for (int c = 0; c < 3; ++c) { Pf[c] = p; p += SEG; }
  for (int c = 0; c < 3; ++c) { Pb[c] = p; p += SEG; }
  float* Hstf = p; p += SEG;
  float* Hstb = p; p += SEG;
  float* Rbuf = p; p += 2*KF;
  // bf16 region
  __hip_bfloat16* bp = (__hip_bfloat16*)p;
  __hip_bfloat16* feat_bf = bp; bp += SEG;
  __hip_bfloat16* tmpA_bf = bp; bp += SEG;
  __hip_bfloat16* tmpB_bf = bp; bp += SEG;
  const size_t WSEG = (size_t)F*F;
  __hip_bfloat16* wT_gcn[2];
  __hip_bfloat16* wT_g[2][3];
  __hip_bfloat16* wT_l[2][3];
  for (int l = 0; l < 2; ++l) { wT_gcn[l] = bp; bp += WSEG; }
  for (int d = 0; d < 2; ++d)
    for (int c = 0; c < 3; ++c) { wT_g[d][c] = bp; bp += WSEG; }
  for (int d = 0; d < 2; ++d)
    for (int c = 0; c < 3; ++c) { wT_l[d][c] = bp; bp += WSEG; }
  __hip_bfloat16* wScan = bp; bp += 6*WSEG; // [d][g] bottom-half lW transposed

  prep_kernel<<<1, 256, 0, stream>>>(A, vid, An, rf, rb, bar);
  downsample_kernel<<<TK, 256, 0, stream>>>(x, feat_bf);

  // weight convert+transpose (src blocks are contiguous FxF fp32)
  dim3 tgrid(32, 32);
  for (int l = 0; l < 2; ++l)
    convt_kernel<<<tgrid, 256, 0, stream>>>(gcn_W + (size_t)l*WSEG, wT_gcn[l]);
  for (int c = 0; c < 3; ++c) {
    convt_kernel<<<tgrid, 256, 0, stream>>>(tf_gW + (size_t)c*WSEG, wT_g[0][c]);
    convt_kernel<<<tgrid, 256, 0, stream>>>(tb_gW + (size_t)c*WSEG, wT_g[1][c]);
    convt_kernel<<<tgrid, 256, 0, stream>>>(tf_lW + (size_t)c*2*WSEG, wT_l[0][c]);          // top F rows
    convt_kernel<<<tgrid, 256, 0, stream>>>(tb_lW + (size_t)c*2*WSEG, wT_l[1][c]);
    convt_kernel<<<tgrid, 256, 0, stream>>>(tf_lW + (size_t)c*2*WSEG + WSEG, wScan + (size_t)(0*3 + c)*WSEG); // bottom F rows
    convt_kernel<<<tgrid, 256, 0, stream>>>(tb_lW + (size_t)c*2*WSEG + WSEG, wScan + (size_t)(1*3 + c)*WSEG);
  }

  dim3 ggrid(F/128, TK/128); // (8, 14)
  // GCN layers
  for (int l = 0; l < 2; ++l) {
    gemm_mfma<1><<<ggrid, 256, 0, stream>>>(feat_bf, wT_gcn[l], nullptr, tmpA_bf, F);
    anmix_kernel<<<T, 256, 0, stream>>>(tmpA_bf, An, gcn_b + (size_t)l*F, feat_bf, 1);
  }
  // Per-direction input-side precompute: conv_c then P_c for all t
  for (int d = 0; d < 2; ++d) {
    const float* gb = d ? tb_gb : tf_gb;
    const float* lb = d ? tb_lb : tf_lb;
    float** Pd = d ? Pb : Pf;
    for (int c = 0; c < 3; ++c) {
      gemm_mfma<1><<<ggrid, 256, 0, stream>>>(feat_bf, wT_g[d][c], nullptr, tmpA_bf, F);
      anmix_kernel<<<T, 256, 0, stream>>>(tmpA_bf, An, gb + (size_t)c*F, tmpB_bf, 0);
      gemm_mfma<0><<<ggrid, 256, 0, stream>>>(tmpB_bf, wT_l[d][c], lb + (size_t)c*F, Pd[c], F);
    }
  }
  // Persistent GRU scan: single dispatch for all 128 steps, both directions
  scan_persist<<<NBLK, 256, 0, stream>>>(Hstf, Hstb, (const short*)wScan,
                                         Pf[0], Pf[1], Pf[2], Pb[0], Pb[1], Pb[2],
                                         rf, rb, Rbuf, bar);
  upsample_kernel<<<TK, 256, 0, stream>>>(Hstf, Hstb, out);
}

// Round 6
// 4287.358 us; speedup vs baseline: 1.2189x; 1.2189x over previous
//
#include <hip/hip_runtime.h>
#include <hip/hip_bf16.h>
#include <math.h>

#define T 128
#define KN 14      // graph nodes
#define HM 64
#define HF 32
#define F 1024
#define TK (T*KN)   // 1792
#define KF (KN*F)   // 14336

typedef __attribute__((ext_vector_type(8))) short bf16x8;
typedef __attribute__((ext_vector_type(4))) float f32x4;
typedef unsigned long long u64;

#define SEGN ((size_t)TK * F)      // 1,835,008 elements
#define WSEGN ((size_t)F * F)      // 1,048,576 elements

// relaxed agent-scope (MALL-coherent) accessors
#define AL_F(p)    __hip_atomic_load((p),  __ATOMIC_RELAXED, __HIP_MEMORY_SCOPE_AGENT)
#define AS_F(p,v)  __hip_atomic_store((p),(v), __ATOMIC_RELAXED, __HIP_MEMORY_SCOPE_AGENT)
#define AL_U64(p)  __hip_atomic_load((p),  __ATOMIC_RELAXED, __HIP_MEMORY_SCOPE_AGENT)
#define AL_I(p)    __hip_atomic_load((p),  __ATOMIC_RELAXED, __HIP_MEMORY_SCOPE_AGENT)
#define AS_I(p,v)  __hip_atomic_store((p),(v), __ATOMIC_RELAXED, __HIP_MEMORY_SCOPE_AGENT)

static __device__ __forceinline__ short f2bs(float f) {
  __hip_bfloat16 h = __float2bfloat16(f);
  return *reinterpret_cast<short*>(&h);
}

// ---------------- prep: An (gcn_norm) + reset flags + barrier flags init ----------------
__global__ void prep_kernel(const float* __restrict__ A, const int* __restrict__ vid,
                            float* __restrict__ An, int* __restrict__ rf, int* __restrict__ rb,
                            int* __restrict__ flags) {
  __shared__ float dinv[KN];
  int tid = threadIdx.x;
  if (tid < 32) flags[tid] = 0;
  if (tid < KN) {
    float s = 0.f;
    for (int j = 0; j < KN; ++j) {
      float ab = (A[tid*KN + j] != 0.f) ? 1.f : 0.f;
      if (j == tid) ab += 1.f;
      s += ab;
    }
    dinv[tid] = 1.0f / sqrtf(s);
  }
  __syncthreads();
  if (tid < KN*KN) {
    int i = tid / KN, j = tid % KN;
    float ab = (A[i*KN + j] != 0.f) ? 1.f : 0.f;
    if (i == j) ab += 1.f;
    An[tid] = dinv[i] * ab * dinv[j];
  }
  if (tid < T) {
    rf[tid] = (tid == 0) || (vid[tid] != vid[tid-1]);
    rb[tid] = (tid == 0) || (vid[T-1-tid] != vid[T-tid]);
  }
}

// ---------------- downsample: x (T,K,64,64) -> feat_bf (T,K,1024) ----------------
__global__ void downsample_kernel(const float* __restrict__ x, __hip_bfloat16* __restrict__ feat) {
  __shared__ float xt[HM*HM];
  int b = blockIdx.x; // t*KN + k
  const float* xp = x + (size_t)b*HM*HM;
  int tid = threadIdx.x;
  #pragma unroll
  for (int i = 0; i < 4; ++i)
    ((float4*)xt)[tid + i*256] = ((const float4*)xp)[tid + i*256];
  __syncthreads();
  const float r = 63.0f/31.0f;
  __hip_bfloat16* fp = feat + (size_t)b*F;
  #pragma unroll
  for (int i = 0; i < 4; ++i) {
    int idx = tid + i*256;
    int o = idx >> 5, p = idx & 31;
    float co = (float)o * r; int io = (int)floorf(co); int io1 = min(io+1, HM-1); float wo = co - (float)io;
    float cp = (float)p * r; int jp = (int)floorf(cp); int jp1 = min(jp+1, HM-1); float wp = cp - (float)jp;
    float v = (1.f-wo)*((1.f-wp)*xt[io*HM+jp]  + wp*xt[io*HM+jp1])
            +      wo *((1.f-wp)*xt[io1*HM+jp] + wp*xt[io1*HM+jp1]);
    fp[idx] = __float2bfloat16(v);
  }
}

// ---------------- batched convert+transpose: 20 FxF fp32 blocks -> bf16 transposed ----------------
struct ConvtJobs { const float* src[20]; short* dst[20]; };
__global__ void convt_all(ConvtJobs j) {
  const float* __restrict__ src = j.src[blockIdx.z];
  short* __restrict__ dst = j.dst[blockIdx.z];
  __shared__ float tile[32][33];
  int bx = blockIdx.x, by = blockIdx.y;
  int tx = threadIdx.x & 31, ty = threadIdx.x >> 5; // ty 0..7
  #pragma unroll
  for (int i = 0; i < 4; ++i)
    tile[ty + i*8][tx] = src[(size_t)(by*32 + ty + i*8)*F + bx*32 + tx];
  __syncthreads();
  #pragma unroll
  for (int i = 0; i < 4; ++i)
    dst[(size_t)(bx*32 + ty + i*8)*F + by*32 + tx] = f2bs(tile[tx][ty + i*8]);
}

// ---------------- bf16 MFMA GEMM body: C(128,128 tile) = A(M,1024) @ Bt(N,1024)^T (+bias) ----------------
template<int OUT_BF16>
static __device__ __forceinline__ void gemm_body(
    const __hip_bfloat16* __restrict__ A, const __hip_bfloat16* __restrict__ Bt,
    const float* __restrict__ bias, void* __restrict__ C) {
  const int Kd = F;
  __shared__ short As[128][40]; // 32 used + pad
  __shared__ short Bs[128][40];
  int tid = threadIdx.x;
  int wave = tid >> 6, lane = tid & 63;
  int mBase = blockIdx.y * 128, nBase = blockIdx.x * 128;
  int srow = tid >> 2;          // 0..63
  int scol = (tid & 3) * 8;     // 0,8,16,24
  int mW = (wave >> 1) * 64, nW = (wave & 1) * 64;
  int fr = lane & 15;
  int fk = (lane >> 4) * 8;
  f32x4 acc[4][4];
  #pragma unroll
  for (int i = 0; i < 4; ++i)
    #pragma unroll
    for (int j = 0; j < 4; ++j)
      acc[i][j] = (f32x4){0.f, 0.f, 0.f, 0.f};
  for (int k0 = 0; k0 < Kd; k0 += 32) {
    float4 a0 = *(const float4*)(A  + (size_t)(mBase + srow)*Kd + k0 + scol);
    float4 a1 = *(const float4*)(A  + (size_t)(mBase + srow + 64)*Kd + k0 + scol);
    float4 b0 = *(const float4*)(Bt + (size_t)(nBase + srow)*Kd + k0 + scol);
    float4 b1 = *(const float4*)(Bt + (size_t)(nBase + srow + 64)*Kd + k0 + scol);
    __syncthreads();
    *(float4*)&As[srow][scol] = a0;
    *(float4*)&As[srow+64][scol] = a1;
    *(float4*)&Bs[srow][scol] = b0;
    *(float4*)&Bs[srow+64][scol] = b1;
    __syncthreads();
    bf16x8 af[4], bfr[4];
    #pragma unroll
    for (int i = 0; i < 4; ++i) af[i]  = *(const bf16x8*)&As[mW + i*16 + fr][fk];
    #pragma unroll
    for (int j = 0; j < 4; ++j) bfr[j] = *(const bf16x8*)&Bs[nW + j*16 + fr][fk];
    #pragma unroll
    for (int i = 0; i < 4; ++i)
      #pragma unroll
      for (int j = 0; j < 4; ++j)
        acc[i][j] = __builtin_amdgcn_mfma_f32_16x16x32_bf16(af[i], bfr[j], acc[i][j], 0, 0, 0);
  }
  int rq = (lane >> 4) * 4;
  int cl = lane & 15;
  float bv[4];
  #pragma unroll
  for (int j = 0; j < 4; ++j) bv[j] = bias ? bias[nBase + nW + j*16 + cl] : 0.f;
  #pragma unroll
  for (int i = 0; i < 4; ++i) {
    #pragma unroll
    for (int r = 0; r < 4; ++r) {
      int row = mBase + mW + i*16 + rq + r;
      #pragma unroll
      for (int j = 0; j < 4; ++j) {
        int col = nBase + nW + j*16 + cl;
        float v = acc[i][j][r] + bv[j];
        if (OUT_BF16)
          ((__hip_bfloat16*)C)[(size_t)row*F + col] = __float2bfloat16(v);
        else
          ((float*)C)[(size_t)row*F + col] = v;
      }
    }
  }
}

__global__ __launch_bounds__(256) void gemm_single_bf16(
    const __hip_bfloat16* __restrict__ A, const __hip_bfloat16* __restrict__ Bt,
    const float* __restrict__ bias, __hip_bfloat16* __restrict__ C) {
  gemm_body<1>(A, Bt, bias, C);
}

// z-batched: C[z] = feat @ wT_g[z]  (fp32 out, no bias)
__global__ __launch_bounds__(256) void gemm_batchA(
    const __hip_bfloat16* __restrict__ feat, const __hip_bfloat16* __restrict__ Wbase,
    float* __restrict__ Cbase) {
  int z = blockIdx.z;
  gemm_body<0>(feat, Wbase + (size_t)z*WSEGN, nullptr, Cbase + (size_t)z*SEGN);
}

// z-batched: C[z] = mix[z] @ wT_l[z] + lb  (fp32 out)
__global__ __launch_bounds__(256) void gemm_batchB(
    const __hip_bfloat16* __restrict__ mixBase, const __hip_bfloat16* __restrict__ Wbase,
    const float* __restrict__ lbf, const float* __restrict__ lbb,
    float* __restrict__ Cbase) {
  int z = blockIdx.z;
  const float* bias = (z < 3) ? (lbf + (size_t)z*F) : (lbb + (size_t)(z-3)*F);
  gemm_body<0>(mixBase + (size_t)z*SEGN, Wbase + (size_t)z*WSEGN, bias, Cbase + (size_t)z*SEGN);
}

// ---------------- An-mix (GCN): bf16 in, bf16 out, bias+relu ----------------
__global__ void anmix_gcn(const __hip_bfloat16* __restrict__ in, const float* __restrict__ An,
                          const float* __restrict__ bias, __hip_bfloat16* __restrict__ out) {
  __shared__ float an[KN*KN];
  int t = blockIdx.x, tid = threadIdx.x;
  if (tid < KN*KN) an[tid] = An[tid];
  __syncthreads();
  const __hip_bfloat16* ip = in + (size_t)t*KF;
  __hip_bfloat16* op = out + (size_t)t*KF;
  #pragma unroll
  for (int i = 0; i < 4; ++i) {
    int f = tid + i*256;
    float v[KN];
    #pragma unroll
    for (int j = 0; j < KN; ++j) v[j] = __bfloat162float(ip[j*F + f]);
    float bsv = bias[f];
    #pragma unroll
    for (int k = 0; k < KN; ++k) {
      float s = bsv;
      #pragma unroll
      for (int j = 0; j < KN; ++j) s = fmaf(an[k*KN+j], v[j], s);
      s = fmaxf(s, 0.f);
      op[k*F + f] = __float2bfloat16(s);
    }
  }
}

// ---------------- z-batched An-mix: fp32 in (Pall), bf16 out (mixBase), +gb bias ----------------
__global__ void anmix6_kernel(const float* __restrict__ Pall, const float* __restrict__ An,
                              const float* __restrict__ gbf, const float* __restrict__ gbb,
                              __hip_bfloat16* __restrict__ mixBase) {
  __shared__ float an[KN*KN];
  int t = blockIdx.x, z = blockIdx.y, tid = threadIdx.x;
  if (tid < KN*KN) an[tid] = An[tid];
  __syncthreads();
  const float* bias = (z < 3) ? (gbf + (size_t)z*F) : (gbb + (size_t)(z-3)*F);
  const float* ip = Pall + (size_t)z*SEGN + (size_t)t*KF;
  __hip_bfloat16* op = mixBase + (size_t)z*SEGN + (size_t)t*KF;
  #pragma unroll
  for (int i = 0; i < 4; ++i) {
    int f = tid + i*256;
    float v[KN];
    #pragma unroll
    for (int j = 0; j < KN; ++j) v[j] = ip[j*F + f];
    float bsv = bias[f];
    #pragma unroll
    for (int k = 0; k < KN; ++k) {
      float s = bsv;
      #pragma unroll
      for (int j = 0; j < KN; ++j) s = fmaf(an[k*KN+j], v[j], s);
      op[k*F + f] = __float2bfloat16(s);
    }
  }
}

// ---------------- persistent GRU scan: flag-array barrier, per-direction ----------------
#define NBLK 32
__global__ __launch_bounds__(256) void scan_persist(
    float* __restrict__ Hstf, float* __restrict__ Hstb,
    const short* __restrict__ wScan,
    const float* __restrict__ Pall,
    const int* __restrict__ rf, const int* __restrict__ rb,
    float* __restrict__ HRbuf, int* __restrict__ flags) {
  int bx = blockIdx.x;     // 0..31
  int d = bx >> 4;
  int cb = bx & 15;        // 64-col chunk
  int tid = threadIdx.x;
  int wave = tid >> 6, lane = tid & 63;
  int cl = lane & 15;
  int kq = (lane >> 4) * 8;
  int rq = (lane >> 4) * 4;
  int colg = cb*64 + wave*16 + cl;
  int myid = d*16 + cb;
  int pollIdx = d*16 + (tid & 15);

  float* Hst = d ? Hstb : Hstf;
  const int* rs = d ? rb : rf;
  const float* P0base = Pall + (size_t)(d*3 + 0)*SEGN;
  const float* P1base = Pall + (size_t)(d*3 + 1)*SEGN;
  const float* P2base = Pall + (size_t)(d*3 + 2)*SEGN;
  float* HRme = HRbuf + (size_t)d*KF;
  const short* W0 = wScan + ((size_t)(d*3 + 0))*WSEGN + (size_t)colg*F + kq;
  const short* W1 = wScan + ((size_t)(d*3 + 1))*WSEGN + (size_t)colg*F + kq;
  const short* W2 = wScan + ((size_t)(d*3 + 2))*WSEGN + (size_t)colg*F + kq;

  __shared__ short Ash[16][1032];
  // zero pad rows 14,15 once (never written again)
  #pragma unroll
  for (int i = 0; i < 8; ++i) {
    int e = tid + i*256;          // 0..2047
    Ash[14 + (e >> 10)][e & 1023] = 0;
  }
  __syncthreads();

  int ph = 0;
  for (int t = 0; t < T; ++t) {
    int reset = rs[t];
    int tt = d ? (T-1-t) : t;
    int prev = d ? (tt+1) : (tt-1);
    const float* Hprev = Hst + (size_t)prev*KF;

    // ---- phase A: Z (regs), HR = H*R (to MALL) ----
    f32x4 accZ = (f32x4){0.f,0.f,0.f,0.f};
    f32x4 accR = (f32x4){0.f,0.f,0.f,0.f};
    if (!reset) {
      // stage full H (14x1024 fp32 = 7168 u64) -> bf16 LDS
      #pragma unroll
      for (int i = 0; i < 28; ++i) {
        int idx2 = tid + i*256;               // u64 index 0..7167
        u64 v = AL_U64((const u64*)Hprev + idx2);
        float2 f = *reinterpret_cast<float2*>(&v);
        int e = idx2 * 2;                     // element index 0..14334
        short2 s; s.x = f2bs(f.x); s.y = f2bs(f.y);
        *(short2*)&Ash[e >> 10][e & 1023] = s;
      }
      __syncthreads();
      #pragma unroll 8
      for (int kc = 0; kc < 32; ++kc) {
        bf16x8 a  = *(const bf16x8*)&Ash[cl][kc*32 + kq];
        bf16x8 b0 = *(const bf16x8*)(W0 + kc*32);
        bf16x8 b1 = *(const bf16x8*)(W1 + kc*32);
        accZ = __builtin_amdgcn_mfma_f32_16x16x32_bf16(a, b0, accZ, 0, 0, 0);
        accR = __builtin_amdgcn_mfma_f32_16x16x32_bf16(a, b1, accR, 0, 0, 0);
      }
    }
    const float* P0 = P0base + (size_t)tt*KF;
    const float* P1 = P1base + (size_t)tt*KF;
    float z[4], heff[4];
    #pragma unroll
    for (int r = 0; r < 4; ++r) {
      int node = rq + r;
      if (node < KN) {
        float h = reset ? 0.f : AL_F(Hprev + node*F + colg);
        heff[r] = h;
        z[r] = 1.f / (1.f + expf(-(P0[node*F + colg] + accZ[r])));
        float rr = 1.f / (1.f + expf(-(P1[node*F + colg] + accR[r])));
        AS_F(HRme + node*F + colg, h * rr);
      }
    }
    // ---- barrier 1 (per-direction flag array) ----
    ++ph;
    __syncthreads();   // drains vmem (release), converges block
    if (tid == 0) AS_I(&flags[myid], ph);
    if (tid < 64) {
      while (AL_I(&flags[pollIdx]) < ph) __builtin_amdgcn_s_sleep(1);
    }
    __syncthreads();

    // ---- phase B: Ht, Hn ----
    f32x4 acc = (f32x4){0.f,0.f,0.f,0.f};
    if (!reset) {
      #pragma unroll
      for (int i = 0; i < 28; ++i) {
        int idx2 = tid + i*256;
        u64 v = AL_U64((const u64*)HRme + idx2);
        float2 f = *reinterpret_cast<float2*>(&v);
        int e = idx2 * 2;
        short2 s; s.x = f2bs(f.x); s.y = f2bs(f.y);
        *(short2*)&Ash[e >> 10][e & 1023] = s;
      }
      __syncthreads();
      #pragma unroll 8
      for (int kc = 0; kc < 32; ++kc) {
        bf16x8 a = *(const bf16x8*)&Ash[cl][kc*32 + kq];
        bf16x8 b = *(const bf16x8*)(W2 + kc*32);
        acc = __builtin_amdgcn_mfma_f32_16x16x32_bf16(a, b, acc, 0, 0, 0);
      }
    }
    const float* P2 = P2base + (size_t)tt*KF;
    float* Hout = Hst + (size_t)tt*KF;
    #pragma unroll
    for (int r = 0; r < 4; ++r) {
      int node = rq + r;
      if (node < KN) {
        float ht = tanhf(P2[node*F + colg] + acc[r]);
        float hn = z[r]*heff[r] + (1.f - z[r])*ht;
        AS_F(Hout + node*F + colg, hn);
      }
    }
    // ---- barrier 2 (skip after last step) ----
    ++ph;
    if (t < T-1) {
      __syncthreads();
      if (tid == 0) AS_I(&flags[myid], ph);
      if (tid < 64) {
        while (AL_I(&flags[pollIdx]) < ph) __builtin_amdgcn_s_sleep(1);
      }
      __syncthreads();
    }
  }
}

// ---------------- upsample + sigmoid: (T,K,32,32)->(T,1,K,64,64) ----------------
__global__ void upsample_kernel(const float* __restrict__ Hf, const float* __restrict__ Hb,
                                float* __restrict__ out) {
  __shared__ float h[HF*HF];
  int b = blockIdx.x; // t*KN + k
  int tid = threadIdx.x;
  #pragma unroll
  for (int i = 0; i < 4; ++i) {
    int idx = tid + i*256;
    h[idx] = Hf[(size_t)b*F + idx] + Hb[(size_t)b*F + idx];
  }
  __syncthreads();
  const float r = 31.0f/63.0f;
  float* op = out + (size_t)b*HM*HM;
  #pragma unroll
  for (int i = 0; i < 16; ++i) {
    int idx = tid + i*256;
    int o = idx >> 6, p = idx & 63;
    float co = (float)o * r; int io = (int)floorf(co); int io1 = min(io+1, HF-1); float wo = co - (float)io;
    float cp = (float)p * r; int jp = (int)floorf(cp); int jp1 = min(jp+1, HF-1); float wp = cp - (float)jp;
    float v = (1.f-wo)*((1.f-wp)*h[io*HF+jp]  + wp*h[io*HF+jp1])
            +      wo *((1.f-wp)*h[io1*HF+jp] + wp*h[io1*HF+jp1]);
    op[idx] = 1.f / (1.f + expf(-v));
  }
}

extern "C" void kernel_launch(void* const* d_in, const int* in_sizes, int n_in,
                              void* d_out, int out_size, void* d_ws, size_t ws_size,
                              hipStream_t stream) {
  const float* x      = (const float*)d_in[0];
  const float* A      = (const float*)d_in[1];
  const float* gcn_W  = (const float*)d_in[2];
  const float* gcn_b  = (const float*)d_in[3];
  const float* tf_gW  = (const float*)d_in[4];
  const float* tf_gb  = (const float*)d_in[5];
  const float* tf_lW  = (const float*)d_in[6];
  const float* tf_lb  = (const float*)d_in[7];
  const float* tb_gW  = (const float*)d_in[8];
  const float* tb_gb  = (const float*)d_in[9];
  const float* tb_lW  = (const float*)d_in[10];
  const float* tb_lb  = (const float*)d_in[11];
  const int*   vid    = (const int*)d_in[12];
  float* out = (float*)d_out;

  float* ws = (float*)d_ws;
  float* An = ws;                  // 196 floats
  int* rf = (int*)(ws + 256);      // 128 ints
  int* rb = (int*)(ws + 512);      // 128 ints
  int* flags = (int*)(ws + 768);   // 32 barrier flags
  float* p = ws + 1024;
  float* Pall = p; p += 6*SEGN;    // [d*3+c] fp32 (gemmA out -> anmix6 in; gemmB out -> scan P)
  float* Hstf = p; p += SEGN;
  float* Hstb = p; p += SEGN;
  float* HRbuf = p; p += 2*KF;
  // bf16 region
  short* bp = (short*)p;
  short* feat_bf = bp; bp += SEGN;
  short* mixBase = bp; bp += 6*SEGN;   // [z] anmix6 out / GCN scratch (seg 0)
  short* wT_gcn = bp; bp += 2*WSEGN;
  short* wT_g   = bp; bp += 6*WSEGN;   // [d*3+c]
  short* wT_l   = bp; bp += 6*WSEGN;   // [d*3+c] top halves
  short* wScan  = bp; bp += 6*WSEGN;   // [d*3+c] bottom halves

  prep_kernel<<<1, 256, 0, stream>>>(A, vid, An, rf, rb, flags);
  downsample_kernel<<<TK, 256, 0, stream>>>(x, (__hip_bfloat16*)feat_bf);

  // batched weight convert+transpose: 20 jobs in one dispatch
  ConvtJobs jobs;
  for (int l = 0; l < 2; ++l) { jobs.src[l] = gcn_W + (size_t)l*WSEGN; jobs.dst[l] = wT_gcn + (size_t)l*WSEGN; }
  for (int dd = 0; dd < 2; ++dd)
    for (int c = 0; c < 3; ++c) {
      int z = dd*3 + c;
      const float* gW = dd ? tb_gW : tf_gW;
      const float* lW = dd ? tb_lW : tf_lW;
      jobs.src[2+z]  = gW + (size_t)c*WSEGN;            jobs.dst[2+z]  = wT_g + (size_t)z*WSEGN;
      jobs.src[8+z]  = lW + (size_t)c*2*WSEGN;          jobs.dst[8+z]  = wT_l + (size_t)z*WSEGN;   // top F rows
      jobs.src[14+z] = lW + (size_t)c*2*WSEGN + WSEGN;  jobs.dst[14+z] = wScan + (size_t)z*WSEGN;  // bottom F rows
    }
  convt_all<<<dim3(32, 32, 20), 256, 0, stream>>>(jobs);

  // GCN layers (sequential; scratch = mixBase seg 0)
  dim3 ggrid(F/128, TK/128); // (8, 14)
  for (int l = 0; l < 2; ++l) {
    gemm_single_bf16<<<ggrid, 256, 0, stream>>>((const __hip_bfloat16*)feat_bf,
        (const __hip_bfloat16*)(wT_gcn + (size_t)l*WSEGN), nullptr, (__hip_bfloat16*)mixBase);
    anmix_gcn<<<T, 256, 0, stream>>>((const __hip_bfloat16*)mixBase, An,
        gcn_b + (size_t)l*F, (__hip_bfloat16*)feat_bf);
  }
  // batched input-side precompute: conv (gemmA) -> An-mix -> P (gemmB), z = d*3+c
  gemm_batchA<<<dim3(F/128, TK/128, 6), 256, 0, stream>>>(
      (const __hip_bfloat16*)feat_bf, (const __hip_bfloat16*)wT_g, Pall);
  anmix6_kernel<<<dim3(T, 6), 256, 0, stream>>>(Pall, An, tf_gb, tb_gb, (__hip_bfloat16*)mixBase);
  gemm_batchB<<<dim3(F/128, TK/128, 6), 256, 0, stream>>>(
      (const __hip_bfloat16*)mixBase, (const __hip_bfloat16*)wT_l, tf_lb, tb_lb, Pall);

  // persistent GRU scan: single dispatch, all 128 steps, both directions
  scan_persist<<<NBLK, 256, 0, stream>>>(Hstf, Hstb, wScan, Pall, rf, rb, HRbuf, flags);

  upsample_kernel<<<TK, 256, 0, stream>>>(Hstf, Hstb, out);
}

// Round 7
// 1384.693 us; speedup vs baseline: 3.7740x; 3.0963x over previous
//
#include <hip/hip_runtime.h>
#include <hip/hip_bf16.h>
#include <math.h>

#define T 128
#define KN 14      // graph nodes
#define HM 64
#define HF 32
#define F 1024
#define TK (T*KN)   // 1792
#define KF (KN*F)   // 14336

typedef __attribute__((ext_vector_type(8))) short bf16x8;
typedef __attribute__((ext_vector_type(4))) float f32x4;
typedef unsigned long long u64;

#define SEGN ((size_t)TK * F)      // 1,835,008 elements
#define WSEGN ((size_t)F * F)      // 1,048,576 elements

// relaxed agent-scope (MALL-coherent) accessors
#define AL_F(p)    __hip_atomic_load((p),  __ATOMIC_RELAXED, __HIP_MEMORY_SCOPE_AGENT)
#define AS_F(p,v)  __hip_atomic_store((p),(v), __ATOMIC_RELAXED, __HIP_MEMORY_SCOPE_AGENT)
#define AL_U64(p)  __hip_atomic_load((p),  __ATOMIC_RELAXED, __HIP_MEMORY_SCOPE_AGENT)
#define AL_I(p)    __hip_atomic_load((p),  __ATOMIC_RELAXED, __HIP_MEMORY_SCOPE_AGENT)
#define AS_I(p,v)  __hip_atomic_store((p),(v), __ATOMIC_RELAXED, __HIP_MEMORY_SCOPE_AGENT)
#define AS_S(p,v)  __hip_atomic_store((p),(v), __ATOMIC_RELAXED, __HIP_MEMORY_SCOPE_AGENT)

static __device__ __forceinline__ short f2bs(float f) {
  __hip_bfloat16 h = __float2bfloat16(f);
  return *reinterpret_cast<short*>(&h);
}

// ---------------- prep: An (gcn_norm) + reset flags + barrier flags init ----------------
__global__ void prep_kernel(const float* __restrict__ A, const int* __restrict__ vid,
                            float* __restrict__ An, int* __restrict__ rf, int* __restrict__ rb,
                            int* __restrict__ flags) {
  __shared__ float dinv[KN];
  int tid = threadIdx.x;
  if (tid < 128) flags[tid] = 0;
  if (tid < KN) {
    float s = 0.f;
    for (int j = 0; j < KN; ++j) {
      float ab = (A[tid*KN + j] != 0.f) ? 1.f : 0.f;
      if (j == tid) ab += 1.f;
      s += ab;
    }
    dinv[tid] = 1.0f / sqrtf(s);
  }
  __syncthreads();
  if (tid < KN*KN) {
    int i = tid / KN, j = tid % KN;
    float ab = (A[i*KN + j] != 0.f) ? 1.f : 0.f;
    if (i == j) ab += 1.f;
    An[tid] = dinv[i] * ab * dinv[j];
  }
  if (tid < T) {
    rf[tid] = (tid == 0) || (vid[tid] != vid[tid-1]);
    rb[tid] = (tid == 0) || (vid[T-1-tid] != vid[T-tid]);
  }
}

// ---------------- downsample: x (T,K,64,64) -> feat_bf (T,K,1024) ----------------
__global__ void downsample_kernel(const float* __restrict__ x, __hip_bfloat16* __restrict__ feat) {
  __shared__ float xt[HM*HM];
  int b = blockIdx.x; // t*KN + k
  const float* xp = x + (size_t)b*HM*HM;
  int tid = threadIdx.x;
  #pragma unroll
  for (int i = 0; i < 4; ++i)
    ((float4*)xt)[tid + i*256] = ((const float4*)xp)[tid + i*256];
  __syncthreads();
  const float r = 63.0f/31.0f;
  __hip_bfloat16* fp = feat + (size_t)b*F;
  #pragma unroll
  for (int i = 0; i < 4; ++i) {
    int idx = tid + i*256;
    int o = idx >> 5, p = idx & 31;
    float co = (float)o * r; int io = (int)floorf(co); int io1 = min(io+1, HM-1); float wo = co - (float)io;
    float cp = (float)p * r; int jp = (int)floorf(cp); int jp1 = min(jp+1, HM-1); float wp = cp - (float)jp;
    float v = (1.f-wo)*((1.f-wp)*xt[io*HM+jp]  + wp*xt[io*HM+jp1])
            +      wo *((1.f-wp)*xt[io1*HM+jp] + wp*xt[io1*HM+jp1]);
    fp[idx] = __float2bfloat16(v);
  }
}

// ---------------- batched convert+transpose: 20 FxF fp32 blocks -> bf16 transposed ----------------
struct ConvtJobs { const float* src[20]; short* dst[20]; };
__global__ void convt_all(ConvtJobs j) {
  const float* __restrict__ src = j.src[blockIdx.z];
  short* __restrict__ dst = j.dst[blockIdx.z];
  __shared__ float tile[32][33];
  int bx = blockIdx.x, by = blockIdx.y;
  int tx = threadIdx.x & 31, ty = threadIdx.x >> 5; // ty 0..7
  #pragma unroll
  for (int i = 0; i < 4; ++i)
    tile[ty + i*8][tx] = src[(size_t)(by*32 + ty + i*8)*F + bx*32 + tx];
  __syncthreads();
  #pragma unroll
  for (int i = 0; i < 4; ++i)
    dst[(size_t)(bx*32 + ty + i*8)*F + by*32 + tx] = f2bs(tile[tx][ty + i*8]);
}

// ---------------- bf16 MFMA GEMM body: C(128,128 tile) = A(M,1024) @ Bt(N,1024)^T (+bias) ----------------
template<int OUT_BF16>
static __device__ __forceinline__ void gemm_body(
    const __hip_bfloat16* __restrict__ A, const __hip_bfloat16* __restrict__ Bt,
    const float* __restrict__ bias, void* __restrict__ C) {
  const int Kd = F;
  __shared__ short As[128][40]; // 32 used + pad
  __shared__ short Bs[128][40];
  int tid = threadIdx.x;
  int wave = tid >> 6, lane = tid & 63;
  int mBase = blockIdx.y * 128, nBase = blockIdx.x * 128;
  int srow = tid >> 2;          // 0..63
  int scol = (tid & 3) * 8;     // 0,8,16,24
  int mW = (wave >> 1) * 64, nW = (wave & 1) * 64;
  int fr = lane & 15;
  int fk = (lane >> 4) * 8;
  f32x4 acc[4][4];
  #pragma unroll
  for (int i = 0; i < 4; ++i)
    #pragma unroll
    for (int j = 0; j < 4; ++j)
      acc[i][j] = (f32x4){0.f, 0.f, 0.f, 0.f};
  for (int k0 = 0; k0 < Kd; k0 += 32) {
    float4 a0 = *(const float4*)(A  + (size_t)(mBase + srow)*Kd + k0 + scol);
    float4 a1 = *(const float4*)(A  + (size_t)(mBase + srow + 64)*Kd + k0 + scol);
    float4 b0 = *(const float4*)(Bt + (size_t)(nBase + srow)*Kd + k0 + scol);
    float4 b1 = *(const float4*)(Bt + (size_t)(nBase + srow + 64)*Kd + k0 + scol);
    __syncthreads();
    *(float4*)&As[srow][scol] = a0;
    *(float4*)&As[srow+64][scol] = a1;
    *(float4*)&Bs[srow][scol] = b0;
    *(float4*)&Bs[srow+64][scol] = b1;
    __syncthreads();
    bf16x8 af[4], bfr[4];
    #pragma unroll
    for (int i = 0; i < 4; ++i) af[i]  = *(const bf16x8*)&As[mW + i*16 + fr][fk];
    #pragma unroll
    for (int j = 0; j < 4; ++j) bfr[j] = *(const bf16x8*)&Bs[nW + j*16 + fr][fk];
    #pragma unroll
    for (int i = 0; i < 4; ++i)
      #pragma unroll
      for (int j = 0; j < 4; ++j)
        acc[i][j] = __builtin_amdgcn_mfma_f32_16x16x32_bf16(af[i], bfr[j], acc[i][j], 0, 0, 0);
  }
  int rq = (lane >> 4) * 4;
  int cl = lane & 15;
  float bv[4];
  #pragma unroll
  for (int j = 0; j < 4; ++j) bv[j] = bias ? bias[nBase + nW + j*16 + cl] : 0.f;
  #pragma unroll
  for (int i = 0; i < 4; ++i) {
    #pragma unroll
    for (int r = 0; r < 4; ++r) {
      int row = mBase + mW + i*16 + rq + r;
      #pragma unroll
      for (int j = 0; j < 4; ++j) {
        int col = nBase + nW + j*16 + cl;
        float v = acc[i][j][r] + bv[j];
        if (OUT_BF16)
          ((__hip_bfloat16*)C)[(size_t)row*F + col] = __float2bfloat16(v);
        else
          ((float*)C)[(size_t)row*F + col] = v;
      }
    }
  }
}

__global__ __launch_bounds__(256) void gemm_single_bf16(
    const __hip_bfloat16* __restrict__ A, const __hip_bfloat16* __restrict__ Bt,
    const float* __restrict__ bias, __hip_bfloat16* __restrict__ C) {
  gemm_body<1>(A, Bt, bias, C);
}

// z-batched: C[z] = feat @ wT_g[z]  (fp32 out, no bias)
__global__ __launch_bounds__(256) void gemm_batchA(
    const __hip_bfloat16* __restrict__ feat, const __hip_bfloat16* __restrict__ Wbase,
    float* __restrict__ Cbase) {
  int z = blockIdx.z;
  gemm_body<0>(feat, Wbase + (size_t)z*WSEGN, nullptr, Cbase + (size_t)z*SEGN);
}

// z-batched: C[z] = mix[z] @ wT_l[z] + lb  (fp32 out)
__global__ __launch_bounds__(256) void gemm_batchB(
    const __hip_bfloat16* __restrict__ mixBase, const __hip_bfloat16* __restrict__ Wbase,
    const float* __restrict__ lbf, const float* __restrict__ lbb,
    float* __restrict__ Cbase) {
  int z = blockIdx.z;
  const float* bias = (z < 3) ? (lbf + (size_t)z*F) : (lbb + (size_t)(z-3)*F);
  gemm_body<0>(mixBase + (size_t)z*SEGN, Wbase + (size_t)z*WSEGN, bias, Cbase + (size_t)z*SEGN);
}

// ---------------- An-mix (GCN): bf16 in, bf16 out, bias+relu ----------------
__global__ void anmix_gcn(const __hip_bfloat16* __restrict__ in, const float* __restrict__ An,
                          const float* __restrict__ bias, __hip_bfloat16* __restrict__ out) {
  __shared__ float an[KN*KN];
  int t = blockIdx.x, tid = threadIdx.x;
  if (tid < KN*KN) an[tid] = An[tid];
  __syncthreads();
  const __hip_bfloat16* ip = in + (size_t)t*KF;
  __hip_bfloat16* op = out + (size_t)t*KF;
  #pragma unroll
  for (int i = 0; i < 4; ++i) {
    int f = tid + i*256;
    float v[KN];
    #pragma unroll
    for (int j = 0; j < KN; ++j) v[j] = __bfloat162float(ip[j*F + f]);
    float bsv = bias[f];
    #pragma unroll
    for (int k = 0; k < KN; ++k) {
      float s = bsv;
      #pragma unroll
      for (int j = 0; j < KN; ++j) s = fmaf(an[k*KN+j], v[j], s);
      s = fmaxf(s, 0.f);
      op[k*F + f] = __float2bfloat16(s);
    }
  }
}

// ---------------- z-batched An-mix: fp32 in (Pall), bf16 out (mixBase), +gb bias ----------------
__global__ void anmix6_kernel(const float* __restrict__ Pall, const float* __restrict__ An,
                              const float* __restrict__ gbf, const float* __restrict__ gbb,
                              __hip_bfloat16* __restrict__ mixBase) {
  __shared__ float an[KN*KN];
  int t = blockIdx.x, z = blockIdx.y, tid = threadIdx.x;
  if (tid < KN*KN) an[tid] = An[tid];
  __syncthreads();
  const float* bias = (z < 3) ? (gbf + (size_t)z*F) : (gbb + (size_t)(z-3)*F);
  const float* ip = Pall + (size_t)z*SEGN + (size_t)t*KF;
  __hip_bfloat16* op = mixBase + (size_t)z*SEGN + (size_t)t*KF;
  #pragma unroll
  for (int i = 0; i < 4; ++i) {
    int f = tid + i*256;
    float v[KN];
    #pragma unroll
    for (int j = 0; j < KN; ++j) v[j] = ip[j*F + f];
    float bsv = bias[f];
    #pragma unroll
    for (int k = 0; k < KN; ++k) {
      float s = bsv;
      #pragma unroll
      for (int j = 0; j < KN; ++j) s = fmaf(an[k*KN+j], v[j], s);
      op[k*F + f] = __float2bfloat16(s);
    }
  }
}

// ---------------- segment-parallel persistent GRU scan ----------------
// 8 groups (4 video-segments x 2 directions) x 16 blocks (64 cols each).
// Exchange via bf16 MALL buffers; own-col H carried in registers.
#define NBLK 128
__global__ __launch_bounds__(256) void scan_persist(
    float* __restrict__ Hstf, float* __restrict__ Hstb,
    const short* __restrict__ wScan,
    const float* __restrict__ Pall,
    const int* __restrict__ rf, const int* __restrict__ rb,
    short* __restrict__ Hx, short* __restrict__ HRx, int* __restrict__ flags) {
  int bx = blockIdx.x;           // 0..127
  int g  = bx >> 4;              // group 0..7
  int cb = bx & 15;              // col chunk in group
  int d  = g & 1;
  int gseg = g >> 1;             // 0..3
  int tid = threadIdx.x;
  int wave = tid >> 6, lane = tid & 63;
  int cl = lane & 15;
  int kq = (lane >> 4) * 8;
  int rq = (lane >> 4) * 4;
  int colg = cb*64 + wave*16 + cl;
  int myid = g*16 + cb;
  int pollBase = g*16;

  float* Hst = d ? Hstb : Hstf;
  const int* rs = d ? rb : rf;
  const float* P0base = Pall + (size_t)(d*3 + 0)*SEGN;
  const float* P1base = Pall + (size_t)(d*3 + 1)*SEGN;
  const float* P2base = Pall + (size_t)(d*3 + 2)*SEGN;
  short* Hxg  = Hx  + (size_t)g*KF;
  short* HRxg = HRx + (size_t)g*KF;
  const short* W0 = wScan + ((size_t)(d*3 + 0))*WSEGN + (size_t)colg*F + kq;
  const short* W1 = wScan + ((size_t)(d*3 + 1))*WSEGN + (size_t)colg*F + kq;
  const short* W2 = wScan + ((size_t)(d*3 + 2))*WSEGN + (size_t)colg*F + kq;

  __shared__ short Ash[16][1032];
  __shared__ int startsL[T+1];
  __shared__ int ScountL;
  // zero pad rows 14,15 once (staging never touches them: e <= 14332)
  #pragma unroll
  for (int i = 0; i < 8; ++i) {
    int e = tid + i*256;          // 0..2047
    Ash[14 + (e >> 10)][e & 1023] = 0;
  }
  if (tid == 0) {
    int S = 0;
    for (int t = 0; t < T; ++t) if (rs[t]) startsL[S++] = t;
    startsL[S] = T;
    ScountL = S;
  }
  __syncthreads();
  int S = ScountL;

  int ph = 0;
  for (int si = gseg; si < S; si += 4) {
    int t0 = startsL[si];
    int t1 = startsL[si+1];
    float heff[4] = {0.f, 0.f, 0.f, 0.f};
    for (int t = t0; t < t1; ++t) {
      bool reset = (t == t0);
      int tt = d ? (T-1-t) : t;
      const float* P0 = P0base + (size_t)tt*KF;
      const float* P1 = P1base + (size_t)tt*KF;
      const float* P2 = P2base + (size_t)tt*KF;

      // ---- phase A: Z (regs), R -> HR = heff*R (bf16 exchange) ----
      f32x4 accZ = (f32x4){0.f,0.f,0.f,0.f};
      f32x4 accR = (f32x4){0.f,0.f,0.f,0.f};
      // hoist P loads (independent of exchange)
      float p0v[4], p1v[4], p2v[4];
      #pragma unroll
      for (int r = 0; r < 4; ++r) {
        int node = rq + r;
        if (node < KN) {
          p0v[r] = P0[node*F + colg];
          p1v[r] = P1[node*F + colg];
          p2v[r] = P2[node*F + colg];
        }
      }
      if (!reset) {
        // stage Hxg (14336 bf16 = 3584 u64) -> LDS, pure copy
        #pragma unroll
        for (int i = 0; i < 14; ++i) {
          int idx4 = tid + i*256;            // u64 index 0..3583
          u64 v = AL_U64((const u64*)Hxg + idx4);
          int e = idx4 * 4;                  // element index, %4==0
          *(u64*)&Ash[e >> 10][e & 1023] = v;
        }
        __syncthreads();
        #pragma unroll 8
        for (int kc = 0; kc < 32; ++kc) {
          bf16x8 a  = *(const bf16x8*)&Ash[cl][kc*32 + kq];
          bf16x8 b0 = *(const bf16x8*)(W0 + kc*32);
          bf16x8 b1 = *(const bf16x8*)(W1 + kc*32);
          accZ = __builtin_amdgcn_mfma_f32_16x16x32_bf16(a, b0, accZ, 0, 0, 0);
          accR = __builtin_amdgcn_mfma_f32_16x16x32_bf16(a, b1, accR, 0, 0, 0);
        }
      }
      float z[4];
      #pragma unroll
      for (int r = 0; r < 4; ++r) {
        int node = rq + r;
        if (node < KN) {
          z[r] = 1.f / (1.f + expf(-(p0v[r] + accZ[r])));
          float rr = 1.f / (1.f + expf(-(p1v[r] + accR[r])));
          AS_S(HRxg + node*F + colg, f2bs(heff[r] * rr));
        }
      }
      // ---- barrier A (group-local) ----
      ++ph;
      __syncthreads();
      if (tid == 0) AS_I(&flags[myid], ph);
      if (tid < 16) {
        while (AL_I(&flags[pollBase + tid]) < ph) __builtin_amdgcn_s_sleep(1);
      }
      __syncthreads();

      // ---- phase B: Ht, Hn ----
      f32x4 acc = (f32x4){0.f,0.f,0.f,0.f};
      if (!reset) {
        #pragma unroll
        for (int i = 0; i < 14; ++i) {
          int idx4 = tid + i*256;
          u64 v = AL_U64((const u64*)HRxg + idx4);
          int e = idx4 * 4;
          *(u64*)&Ash[e >> 10][e & 1023] = v;
        }
        __syncthreads();
        #pragma unroll 8
        for (int kc = 0; kc < 32; ++kc) {
          bf16x8 a = *(const bf16x8*)&Ash[cl][kc*32 + kq];
          bf16x8 b = *(const bf16x8*)(W2 + kc*32);
          acc = __builtin_amdgcn_mfma_f32_16x16x32_bf16(a, b, acc, 0, 0, 0);
        }
      }
      float* HoutF = Hst + (size_t)tt*KF;
      #pragma unroll
      for (int r = 0; r < 4; ++r) {
        int node = rq + r;
        if (node < KN) {
          float ht = tanhf(p2v[r] + acc[r]);
          float hn = z[r]*heff[r] + (1.f - z[r])*ht;
          heff[r] = hn;                            // carry in regs
          HoutF[node*F + colg] = hn;               // plain store (read by upsample)
          AS_S(Hxg + node*F + colg, f2bs(hn));     // bf16 exchange for next step
        }
      }
      // ---- barrier B (group-local) ----
      ++ph;
      __syncthreads();
      if (tid == 0) AS_I(&flags[myid], ph);
      if (tid < 16) {
        while (AL_I(&flags[pollBase + tid]) < ph) __builtin_amdgcn_s_sleep(1);
      }
      __syncthreads();
    }
  }
}

// ---------------- upsample + sigmoid: (T,K,32,32)->(T,1,K,64,64) ----------------
__global__ void upsample_kernel(const float* __restrict__ Hf, const float* __restrict__ Hb,
                                float* __restrict__ out) {
  __shared__ float h[HF*HF];
  int b = blockIdx.x; // t*KN + k
  int tid = threadIdx.x;
  #pragma unroll
  for (int i = 0; i < 4; ++i) {
    int idx = tid + i*256;
    h[idx] = Hf[(size_t)b*F + idx] + Hb[(size_t)b*F + idx];
  }
  __syncthreads();
  const float r = 31.0f/63.0f;
  float* op = out + (size_t)b*HM*HM;
  #pragma unroll
  for (int i = 0; i < 16; ++i) {
    int idx = tid + i*256;
    int o = idx >> 6, p = idx & 63;
    float co = (float)o * r; int io = (int)floorf(co); int io1 = min(io+1, HF-1); float wo = co - (float)io;
    float cp = (float)p * r; int jp = (int)floorf(cp); int jp1 = min(jp+1, HF-1); float wp = cp - (float)jp;
    float v = (1.f-wo)*((1.f-wp)*h[io*HF+jp]  + wp*h[io*HF+jp1])
            +      wo *((1.f-wp)*h[io1*HF+jp] + wp*h[io1*HF+jp1]);
    op[idx] = 1.f / (1.f + expf(-v));
  }
}

extern "C" void kernel_launch(void* const* d_in, const int* in_sizes, int n_in,
                              void* d_out, int out_size, void* d_ws, size_t ws_size,
                              hipStream_t stream) {
  const float* x      = (const float*)d_in[0];
  const float* A      = (const float*)d_in[1];
  const float* gcn_W  = (const float*)d_in[2];
  const float* gcn_b  = (const float*)d_in[3];
  const float* tf_gW  = (const float*)d_in[4];
  const float* tf_gb  = (const float*)d_in[5];
  const float* tf_lW  = (const float*)d_in[6];
  const float* tf_lb  = (const float*)d_in[7];
  const float* tb_gW  = (const float*)d_in[8];
  const float* tb_gb  = (const float*)d_in[9];
  const float* tb_lW  = (const float*)d_in[10];
  const float* tb_lb  = (const float*)d_in[11];
  const int*   vid    = (const int*)d_in[12];
  float* out = (float*)d_out;

  float* ws = (float*)d_ws;
  float* An = ws;                  // 196 floats
  int* rf = (int*)(ws + 256);      // 128 ints
  int* rb = (int*)(ws + 512);      // 128 ints
  int* flags = (int*)(ws + 768);   // 128 barrier flags (64B per group)
  float* p = ws + 1024;
  float* Pall = p; p += 6*SEGN;    // [d*3+c] fp32 (gemmA out -> anmix6 in; gemmB out -> scan P)
  float* Hstf = p; p += SEGN;
  float* Hstb = p; p += SEGN;
  // bf16 region
  short* bp = (short*)p;
  short* feat_bf = bp; bp += SEGN;
  short* mixBase = bp; bp += 6*SEGN;   // [z] anmix6 out / GCN scratch (seg 0)
  short* wT_gcn = bp; bp += 2*WSEGN;
  short* wT_g   = bp; bp += 6*WSEGN;   // [d*3+c]
  short* wT_l   = bp; bp += 6*WSEGN;   // [d*3+c] top halves
  short* wScan  = bp; bp += 6*WSEGN;   // [d*3+c] bottom halves
  short* Hx     = bp; bp += 8*KF;      // per-group bf16 H exchange
  short* HRx    = bp; bp += 8*KF;      // per-group bf16 H*R exchange

  prep_kernel<<<1, 256, 0, stream>>>(A, vid, An, rf, rb, flags);
  downsample_kernel<<<TK, 256, 0, stream>>>(x, (__hip_bfloat16*)feat_bf);

  // batched weight convert+transpose: 20 jobs in one dispatch
  ConvtJobs jobs;
  for (int l = 0; l < 2; ++l) { jobs.src[l] = gcn_W + (size_t)l*WSEGN; jobs.dst[l] = wT_gcn + (size_t)l*WSEGN; }
  for (int dd = 0; dd < 2; ++dd)
    for (int c = 0; c < 3; ++c) {
      int z = dd*3 + c;
      const float* gW = dd ? tb_gW : tf_gW;
      const float* lW = dd ? tb_lW : tf_lW;
      jobs.src[2+z]  = gW + (size_t)c*WSEGN;            jobs.dst[2+z]  = wT_g + (size_t)z*WSEGN;
      jobs.src[8+z]  = lW + (size_t)c*2*WSEGN;          jobs.dst[8+z]  = wT_l + (size_t)z*WSEGN;   // top F rows
      jobs.src[14+z] = lW + (size_t)c*2*WSEGN + WSEGN;  jobs.dst[14+z] = wScan + (size_t)z*WSEGN;  // bottom F rows
    }
  convt_all<<<dim3(32, 32, 20), 256, 0, stream>>>(jobs);

  // GCN layers (sequential; scratch = mixBase seg 0)
  dim3 ggrid(F/128, TK/128); // (8, 14)
  for (int l = 0; l < 2; ++l) {
    gemm_single_bf16<<<ggrid, 256, 0, stream>>>((const __hip_bfloat16*)feat_bf,
        (const __hip_bfloat16*)(wT_gcn + (size_t)l*WSEGN), nullptr, (__hip_bfloat16*)mixBase);
    anmix_gcn<<<T, 256, 0, stream>>>((const __hip_bfloat16*)mixBase, An,
        gcn_b + (size_t)l*F, (__hip_bfloat16*)feat_bf);
  }
  // batched input-side precompute: conv (gemmA) -> An-mix -> P (gemmB), z = d*3+c
  gemm_batchA<<<dim3(F/128, TK/128, 6), 256, 0, stream>>>(
      (const __hip_bfloat16*)feat_bf, (const __hip_bfloat16*)wT_g, Pall);
  anmix6_kernel<<<dim3(T, 6), 256, 0, stream>>>(Pall, An, tf_gb, tb_gb, (__hip_bfloat16*)mixBase);
  gemm_batchB<<<dim3(F/128, TK/128, 6), 256, 0, stream>>>(
      (const __hip_bfloat16*)mixBase, (const __hip_bfloat16*)wT_l, tf_lb, tb_lb, Pall);

  // segment-parallel persistent GRU scan: single dispatch
  scan_persist<<<NBLK, 256, 0, stream>>>(Hstf, Hstb, wScan, Pall, rf, rb, Hx, HRx, flags);

  upsample_kernel<<<TK, 256, 0, stream>>>(Hstf, Hstb, out);
}